// Round 1
// 1285.918 us; speedup vs baseline: 1.0062x; 1.0062x over previous
//
#include <hip/hip_runtime.h>
#include <stdint.h>

typedef unsigned int u32;
typedef unsigned short u16;
typedef __attribute__((ext_vector_type(8))) short short8;
typedef __attribute__((ext_vector_type(4))) float f32x4;

#define N_NODESC 30522
#define HIDC 768
#define NEC 488352
#define TOKM 2048
#define LLAY 12
#define NCLS 101
#define M_PAD 30720     // 120*256
#define ZNC (LLAY*HIDC) // 9216
#define OUT_SET (LLAY*4*513*HIDC)
#define PN_KCHUNK 512
#define NBLK 120
#define NN1 (N_NODESC+1)
#define G8_LDS 131072

// ---------- helpers ----------
__device__ __forceinline__ float bl(u32 u){ return __uint_as_float(u<<16); }
__device__ __forceinline__ float bh(u32 u){ return __uint_as_float(u & 0xffff0000u); }
__device__ __forceinline__ u32 f2b1(float f){ u32 x=__float_as_uint(f); return (x + 0x7fffu + ((x>>16)&1u))>>16; }
__device__ __forceinline__ u32 pack2(float a, float b){ return f2b1(a) | (f2b1(b)<<16); }

__device__ __forceinline__ void mfma16(f32x4& d, short8 a, short8 b){
  asm volatile("v_mfma_f32_16x16x32_bf16 %0, %1, %2, %0" : "+v"(d) : "v"(a), "v"(b));
}
__device__ __forceinline__ void async16(const void* g, void* l){
  __builtin_amdgcn_global_load_lds((const __attribute__((address_space(1))) u32*)g,
                                   (__attribute__((address_space(3))) u32*)l, 16, 0, 0);
}

// ---------- mask normalize ----------
__global__ void k_invmask(const void* __restrict__ mask, float* __restrict__ invm){
  __shared__ int s_byte, s_flt;
  int t = threadIdx.x;
  const unsigned char* mb = (const unsigned char*)mask;
  const u32* mw = (const u32*)mask;
  int lb=0, lf=0;
  for(int i=t;i<2048;i+=256) if((i&3)!=0 && mb[i]!=0) lb=1;
  for(int i=t;i<512;i+=256) if(mw[i]==0x3F800000u) lf=1;
  if(t==0){ s_byte=0; s_flt=0; }
  __syncthreads();
  if(lb) s_byte=1;
  if(lf) s_flt=1;
  __syncthreads();
  int mode = s_flt ? 2 : (s_byte ? 1 : 0);
  for(int p=t;p<2048;p+=256){
    int mv = (mode==1) ? (int)mb[p] : (int)(mw[p]!=0u);
    invm[p] = mv ? 0.f : 1.f;
  }
}

__global__ void k_needed(const int* __restrict__ ids, u32* __restrict__ needed){
  int p = blockIdx.x*256 + threadIdx.x;
  if(p < TOKM){ int id = ids[p]; if(id < N_NODESC) needed[id] = 1u; }
}

// ---------- converts ----------
__global__ void k_conv(const float* __restrict__ src, u16* __restrict__ dst, int ndw){
  int i = blockIdx.x*256 + threadIdx.x;
  if(i < ndw) ((u32*)dst)[i] = pack2(src[2*i], src[2*i+1]);
}
__global__ void k_conv_pad(const float* __restrict__ src, u16* __restrict__ dst, int srcRows, int padRows){
  int i = blockIdx.x*256 + threadIdx.x;
  if(i >= padRows*384) return;
  int row = i/384; int c2 = (i - row*384)*2;
  float lo=0.f, hi=0.f;
  if(row < srcRows){ const float* s = src + (size_t)row*HIDC + c2; lo=s[0]; hi=s[1]; }
  ((u32*)dst)[i] = pack2(lo, hi);
}
__global__ void k_pnb(const float* __restrict__ png, u16* __restrict__ pnb){
  int i = blockIdx.x*256 + threadIdx.x;
  if(i >= 128*(M_PAD/2)) return;
  int row = i/(M_PAD/2); int k2 = (i - row*(M_PAD/2))*2;
  float lo=0.f, hi=0.f;
  if(row < NCLS){
    const float* s = png + (size_t)row*N_NODESC;
    if(k2 < N_NODESC) lo = s[k2];
    if(k2+1 < N_NODESC) hi = s[k2+1];
  }
  ((u32*)pnb)[i] = pack2(lo, hi);
}
__global__ void k_transposeW2(const float* __restrict__ coW, const float* __restrict__ reW,
                              u16* __restrict__ Wt2){
  int g = blockIdx.y;
  int i = blockIdx.x*256 + threadIdx.x;
  if(i >= 3*HIDC*384) return;
  const float* W = g ? reW : coW;
  int mat = i/(HIDC*384); int rem = i - mat*HIDC*384;
  int n = rem/384; int kd = rem - n*384;
  const float* Wm = W + (size_t)mat*HIDC*HIDC;
  float lo = Wm[(size_t)(2*kd)*HIDC + n];
  float hi = Wm[(size_t)(2*kd+1)*HIDC + n];
  ((u32*)Wt2)[(size_t)g*3*HIDC*384 + (size_t)mat*HIDC*384 + (size_t)n*384 + kd] = pack2(lo, hi);
}

// ---------- batched graph prep ----------
__global__ void k_degcnt2(const int* __restrict__ coei, const int* __restrict__ reei,
                          const float* __restrict__ coew, const float* __restrict__ reew,
                          float* __restrict__ deg2, int* __restrict__ cnt2){
  int g = blockIdx.y;
  const int* ei = g ? reei : coei;
  const float* ew = g ? reew : coew;
  int e = blockIdx.x*256 + threadIdx.x;
  if(e < NEC){ int d = ei[NEC+e]; atomicAdd(&deg2[(size_t)g*N_NODESC + d], ew[e]); atomicAdd(&cnt2[(size_t)g*N_NODESC + d], 1); }
}
__global__ void k_dinv2(const float* __restrict__ deg2, float* __restrict__ dinvA, float* __restrict__ dinvB){
  int g = blockIdx.y;
  int v = blockIdx.x*256 + threadIdx.x;
  if(v < N_NODESC){
    float d = deg2[(size_t)g*N_NODESC + v] + 1.f;
    dinvA[(size_t)g*N_NODESC + v] = rsqrtf(d);
    dinvB[(size_t)g*N_NODESC + v] = 1.f/d;
  }
}
__global__ void k_scan1(const int* __restrict__ cnt2, int* __restrict__ part2){
  __shared__ int wt[4];
  int g = blockIdx.y, b = blockIdx.x, t = threadIdx.x;
  int lane = t & 63, w = t >> 6;
  int i = b*256 + t;
  int v = (i < N_NODESC) ? cnt2[(size_t)g*N_NODESC + i] : 0;
  int x = v;
  #pragma unroll
  for(int off=1; off<64; off<<=1){ int y = __shfl_up(x, off); if(lane>=off) x += y; }
  if(lane==63) wt[w] = x;
  __syncthreads();
  if(t==0) part2[g*NBLK + b] = wt[0]+wt[1]+wt[2]+wt[3];
}
__global__ void k_scan2(int* __restrict__ part2, int* __restrict__ rp2){
  __shared__ int w0tot;
  int g = blockIdx.x, t = threadIdx.x;   // 128 threads
  int lane = t & 63, w = t >> 6;
  int v = (t < NBLK) ? part2[g*NBLK + t] : 0;
  int x = v;
  #pragma unroll
  for(int off=1; off<64; off<<=1){ int y = __shfl_up(x, off); if(lane>=off) x += y; }
  if(w==0 && lane==63) w0tot = x;
  __syncthreads();
  int incl = x + (w ? w0tot : 0);
  int excl = incl - v;
  if(t < NBLK) part2[g*NBLK + t] = excl;
  if(t == 127) rp2[(size_t)g*NN1 + N_NODESC] = incl;
}
__global__ void k_scan3(const int* __restrict__ cnt2, const int* __restrict__ part2,
                        int* __restrict__ rp2, int* __restrict__ cur2){
  __shared__ int wt[4];
  int g = blockIdx.y, b = blockIdx.x, t = threadIdx.x;
  int lane = t & 63, w = t >> 6;
  int i = b*256 + t;
  int v = (i < N_NODESC) ? cnt2[(size_t)g*N_NODESC + i] : 0;
  int x = v;
  #pragma unroll
  for(int off=1; off<64; off<<=1){ int y = __shfl_up(x, off); if(lane>=off) x += y; }
  if(lane==63) wt[w] = x;
  __syncthreads();
  int wpre = 0;
  #pragma unroll
  for(int j=0;j<4;j++) if(j<w) wpre += wt[j];
  int excl = x - v + wpre + part2[g*NBLK + b];
  if(i < N_NODESC){ rp2[(size_t)g*NN1 + i] = excl; cur2[(size_t)g*N_NODESC + i] = excl; }
}
__global__ void k_scatter2(const int* __restrict__ coei, const int* __restrict__ reei,
                           const float* __restrict__ coew, const float* __restrict__ reew,
                           const float* __restrict__ dinvA, int* __restrict__ cur2,
                           float2* __restrict__ emeta){
  int g = blockIdx.y;
  const int* ei = g ? reei : coei;
  const float* ew = g ? reew : coew;
  int e = blockIdx.x*256 + threadIdx.x;
  if(e < NEC){
    int s = ei[e], d = ei[NEC+e];
    int pos = atomicAdd(&cur2[(size_t)g*N_NODESC + d], 1);
    float nrm = dinvA[(size_t)g*N_NODESC + s]*ew[e]*dinvA[(size_t)g*N_NODESC + d];
    emeta[(size_t)g*NEC + pos] = make_float2(__int_as_float(s), nrm);
  }
}

// ---------- SpMM ----------
__global__ __launch_bounds__(256)
void k_spmm(const u16* __restrict__ hW, const int* __restrict__ rp,
            const float2* __restrict__ emeta, const float* __restrict__ dinv2,
            const float* __restrict__ bias, u16* __restrict__ hout,
            const u32* __restrict__ needed){
  int v = blockIdx.x*4 + (threadIdx.x>>6);
  if(v >= N_NODESC) return;
  if(needed && !needed[v]) return;
  int lane = threadIdx.x & 63;
  const u32* H = (const u32*)hW;
  float acc[12];
  #pragma unroll
  for(int q=0;q<12;q++) acc[q]=0.f;
  int e0 = rp[v], e1 = rp[v+1];
  int e = e0;
  for(; e+4<=e1; e+=4){
    float2 m0=emeta[e], m1=emeta[e+1], m2=emeta[e+2], m3=emeta[e+3];
    const u32* r0 = H + (size_t)__float_as_int(m0.x)*384 + lane;
    const u32* r1 = H + (size_t)__float_as_int(m1.x)*384 + lane;
    const u32* r2 = H + (size_t)__float_as_int(m2.x)*384 + lane;
    const u32* r3 = H + (size_t)__float_as_int(m3.x)*384 + lane;
    u32 u0[6],u1[6],u2[6],u3[6];
    #pragma unroll
    for(int q=0;q<6;q++){ u0[q]=r0[q*64]; u1[q]=r1[q*64]; u2[q]=r2[q*64]; u3[q]=r3[q*64]; }
    #pragma unroll
    for(int q=0;q<6;q++){
      acc[2*q]   += m0.y*bl(u0[q]) + m1.y*bl(u1[q]) + m2.y*bl(u2[q]) + m3.y*bl(u3[q]);
      acc[2*q+1] += m0.y*bh(u0[q]) + m1.y*bh(u1[q]) + m2.y*bh(u2[q]) + m3.y*bh(u3[q]);
    }
  }
  for(; e<e1; ++e){
    float2 mm = emeta[e];
    const u32* r = H + (size_t)__float_as_int(mm.x)*384 + lane;
    #pragma unroll
    for(int q=0;q<6;q++){ u32 u = r[q*64]; acc[2*q] += mm.y*bl(u); acc[2*q+1] += mm.y*bh(u); }
  }
  { float wgt = dinv2[v];
    const u32* r = H + (size_t)v*384 + lane;
    #pragma unroll
    for(int q=0;q<6;q++){ u32 u = r[q*64]; acc[2*q] += wgt*bl(u); acc[2*q+1] += wgt*bh(u); }
  }
  const float2* B2 = (const float2*)bias;
  u32* O = (u32*)hout + (size_t)v*384 + lane;
  #pragma unroll
  for(int q=0;q<6;q++){
    float2 bb = B2[lane + 64*q];
    float x0 = fmaxf(acc[2*q]+bb.x, 0.f);
    float x1 = fmaxf(acc[2*q+1]+bb.y, 0.f);
    O[q*64] = pack2(x0, x1);
  }
}

// ---------- token gather ----------
__global__ void k_gather(const u16* __restrict__ h, const int* __restrict__ ids,
                         float2* __restrict__ tokf, u16* __restrict__ tokb, int phase){
  int d = blockIdx.x*256 + threadIdx.x;
  if(d >= TOKM*384) return;
  int p = d/384, q = d - p*384;
  int id = ids[p];
  float x0=0.f, x1=0.f;
  if(id < N_NODESC){ u32 u = ((const u32*)h)[(size_t)id*384 + q]; x0 = bl(u)*(1.f/3.f); x1 = bh(u)*(1.f/3.f); }
  float2 cur;
  if(phase==0){ cur.x=x0; cur.y=x1; }
  else { cur = tokf[d]; cur.x += x0; cur.y += x1; }
  if(phase==2) ((u32*)tokb)[d] = pack2(cur.x, cur.y);
  else tokf[d] = cur;
}

__global__ void k_gather_pn(const float* __restrict__ GT, const int* __restrict__ cids, u16* __restrict__ tokb){
  int d = blockIdx.x*256 + threadIdx.x;
  if(d >= TOKM*384) return;
  int p = d/384, q = d - p*384;
  int cid = cids[p];
  float lo = GT[(size_t)(2*q)*128 + cid];
  float hi = GT[(size_t)(2*q+1)*128 + cid];
  ((u32*)tokb)[d] = pack2(lo, hi);
}

__global__ void k_zerocol(float* __restrict__ out){
  int i = blockIdx.x*256 + threadIdx.x;
  if(i >= 3*LLAY*4*HIDC) return;
  int set = i/(LLAY*4*HIDC); int rem = i - set*(LLAY*4*HIDC);
  int l = rem/(4*HIDC); int rem2 = rem - l*(4*HIDC);
  int b = rem2/HIDC; int o = rem2 - b*HIDC;
  out[(size_t)set*OUT_SET + (size_t)(l*4+b)*513*HIDC + o] = 0.f;
}

// ================= 8-phase 256x256 GEMM core =================
// LDS map (bytes): A buf b: b*65536 + half*16384 ; B buf b: b*65536+32768 + half*16384
// swizzle: byte ^= ((row&7)<<4)  -> staged via pre-swizzled global source (involution)
#define G8_AOFF(b) ((b)*65536)
#define G8_BOFF(b) ((b)*65536 + 32768)

__device__ __forceinline__ void g8_stage(const u16* __restrict__ src, int ldk, int g0, int kt,
                                         char* half_base, int tid){
  const int lane = tid & 63;
  const int csw = ((lane&7) ^ (lane>>3)) << 3;   // pre-swizzled source col (elements)
  const u16* s0 = src + (size_t)(g0 + (tid>>3))*ldk + (kt + csw);
  const u16* s1 = src + (size_t)(g0 + 64 + (tid>>3))*ldk + (kt + csw);
  async16(s0, half_base + (size_t)tid*16);
  async16(s1, half_base + 8192 + (size_t)tid*16);
}

__device__ __forceinline__ void g8_core(const u16* __restrict__ A, const u16* __restrict__ Bt,
                                        int K, int m0, int n0,
                                        f32x4 (&acc)[8][4], char* LDS, int tid){
  const int lane = tid & 63;
  const int wid = tid >> 6;
  const int wr = wid >> 2, wc = wid & 3;
  const int NK = K >> 6;   // K-tiles (BK=64); requires NK>=3, even

  // prologue: B(0)h0,h1 A(0)h0,h1 B(1)h0,h1 ; vmcnt(4) ; barrier
  g8_stage(Bt, K, n0,      0, LDS + G8_BOFF(0),         tid);
  g8_stage(Bt, K, n0+128,  0, LDS + G8_BOFF(0) + 16384, tid);
  g8_stage(A,  K, m0,      0, LDS + G8_AOFF(0),         tid);
  g8_stage(A,  K, m0+128,  0, LDS + G8_AOFF(0) + 16384, tid);
  g8_stage(Bt, K, n0,     64, LDS + G8_BOFF(1),         tid);
  g8_stage(Bt, K, n0+128, 64, LDS + G8_BOFF(1) + 16384, tid);
  asm volatile("s_waitcnt vmcnt(4)" ::: "memory");
  __builtin_amdgcn_sched_barrier(0);
  __builtin_amdgcn_s_barrier();
  __builtin_amdgcn_sched_barrier(0);

  short8 bf8[8];
  for(int T=0; T<NK; ++T){
    const int buf = T & 1;
    const char* Ab = LDS + G8_AOFF(buf) + wr*16384;
    const char* Bb = LDS + G8_BOFF(buf) + (wc>>1)*16384;
    #pragma unroll
    for(int q=0; q<4; ++q){
      // ---- ds-reads for this phase ----
      if(q==0){
        #pragma unroll
        for(int n=0;n<4;n++){
          #pragma unroll
          for(int kk=0;kk<2;kk++){
            int row = ((wc&1)<<6) + (n<<4) + (lane&15);
            int cb = ((kk<<6) + ((lane>>4)<<4)) ^ ((lane&7)<<4);
            bf8[n*2+kk] = *(const short8*)(Bb + row*128 + cb);
          }
        }
      }
      short8 af[2][2];
      #pragma unroll
      for(int j=0;j<2;j++){
        #pragma unroll
        for(int kk=0;kk<2;kk++){
          int row = ((2*q+j)<<4) + (lane&15);
          int cb = ((kk<<6) + ((lane>>4)<<4)) ^ ((lane&7)<<4);
          af[j][kk] = *(const short8*)(Ab + row*128 + cb);
        }
      }
      // ---- stage schedule: q0:A(T+1)h0 q1:A(T+1)h1 q2:B(T+2)h0 q3:B(T+2)h1 ----
      if(q==0 && T+1<NK) g8_stage(A,  K, m0,      (T+1)<<6, LDS + G8_AOFF((T+1)&1),         tid);
      if(q==1 && T+1<NK) g8_stage(A,  K, m0+128,  (T+1)<<6, LDS + G8_AOFF((T+1)&1) + 16384, tid);
      if(q==2 && T+2<NK) g8_stage(Bt, K, n0,      (T+2)<<6, LDS + G8_BOFF(buf),             tid);
      if(q==3 && T+2<NK) g8_stage(Bt, K, n0+128,  (T+2)<<6, LDS + G8_BOFF(buf) + 16384,     tid);
      if(q==3){
        if(T <= NK-3)      asm volatile("s_waitcnt vmcnt(4)" ::: "memory");
        else if(T == NK-2) asm volatile("s_waitcnt vmcnt(0)" ::: "memory");
      }
      __builtin_amdgcn_sched_barrier(0);
      __builtin_amdgcn_s_barrier();
      __builtin_amdgcn_sched_barrier(0);
      __builtin_amdgcn_s_setprio(1);
      #pragma unroll
      for(int j=0;j<2;j++){
        #pragma unroll
        for(int n=0;n<4;n++){
          #pragma unroll
          for(int kk=0;kk<2;kk++) mfma16(acc[2*q+j][n], af[j][kk], bf8[n*2+kk]);
        }
      }
      __builtin_amdgcn_s_setprio(0);
      __builtin_amdgcn_sched_barrier(0);
      __builtin_amdgcn_s_barrier();
      __builtin_amdgcn_sched_barrier(0);
    }
  }
}

__device__ __forceinline__ void g8_split(int ntM, int ntN, int& bm, int& bn){
  int nwg = ntM*ntN;                       // must be %8==0 (360, 288)
  int bid = (int)blockIdx.x;
  int wg = (bid & 7)*(nwg>>3) + (bid>>3);  // XCD-chunked, bijective
  if(ntN <= ntM){ bm = wg/ntN; bn = wg - bm*ntN; }
  else          { bn = wg/ntM; bm = wg - bn*ntM; }
}

// MODE 0: bf16 out [M,N] ; MODE 2: bf16 out + per-row bias
template<int MODE>
__global__ __launch_bounds__(512,2)
void gemm8p_bf16(const u16* __restrict__ A, const u16* __restrict__ Bt,
                 int M, int N, int K,
                 u16* __restrict__ outB, const float* __restrict__ bias){
  extern __shared__ char LDS[];
  const int tid = threadIdx.x;
  const int lane = tid & 63;
  const int wid = tid >> 6;
  const int wr = wid >> 2, wc = wid & 3;
  int bm, bn;
  g8_split(M>>8, N>>8, bm, bn);
  const int m0 = bm << 8, n0 = bn << 8;

  f32x4 acc[8][4];
  f32x4 zv = {0.f,0.f,0.f,0.f};
  #pragma unroll
  for(int m=0;m<8;m++){
    #pragma unroll
    for(int n=0;n<4;n++) acc[m][n] = zv;
  }
  g8_core(A, Bt, K, m0, n0, acc, LDS, tid);

  const int rbase = (lane>>4)<<2;
  const int cbase = lane & 15;
  #pragma unroll
  for(int m=0;m<8;m++){
    int row0 = m0 + (wr<<7) + (m<<4) + rbase;
    #pragma unroll
    for(int n=0;n<4;n++){
      int col = n0 + (wc<<6) + (n<<4) + cbase;
      #pragma unroll
      for(int r=0;r<4;r++){
        float v = acc[m][n][r];
        if(MODE==2) v += bias[row0+r];
        outB[(size_t)(row0+r)*N + col] = (u16)f2b1(v);
      }
    }
  }
}

// zero-conv epilogue version (3 sets via blockIdx.z)
// Epilogue v2: LDS-staged coalesced fp32 stores.
//   After g8_core, LDS is free (128 KiB). Two passes keyed by wr:
//   pass p stages local rows 0..127 (= global rows m0+p*128 ..) as fp32[128][256]
//   with a 16B-granularity XOR swizzle (^ (lr&7)<<4) to keep LDS 2-way-free.
//   Store phase: each wave stores 16 rows as full 1024B contiguous runs
//   (global_store_dwordx4, 8 full 128B lines per instr) -> no partial-line RMW.
//   n0 is 256-aligned and HID=768=3*256, so a block's 256-col span has fixed l/oc0.
__global__ __launch_bounds__(512,2)
void gemm8p_zc(const u16* __restrict__ TOKALL, const u16* __restrict__ ZWALL,
               const float* __restrict__ zb, const float* __restrict__ zbp,
               const float* __restrict__ invm, float* __restrict__ out){
  extern __shared__ char LDS[];
  const int set = blockIdx.z;
  const u16* A  = TOKALL + (size_t)set*TOKM*HIDC;
  const u16* Bt = ZWALL + (set==2 ? (size_t)ZNC*HIDC : 0);
  const float* bias = (set==2) ? zbp : zb;
  const bool use_mask = (set != 2);
  float* o = out + (size_t)set*OUT_SET;

  const int tid = threadIdx.x;
  const int lane = tid & 63;
  const int wid = tid >> 6;
  const int wr = wid >> 2, wc = wid & 3;
  int bm, bn;
  g8_split(TOKM>>8, ZNC>>8, bm, bn);     // 8 x 36
  const int m0 = bm << 8, n0 = bn << 8;

  f32x4 acc[8][4];
  f32x4 zv = {0.f,0.f,0.f,0.f};
  #pragma unroll
  for(int m=0;m<8;m++){
    #pragma unroll
    for(int n=0;n<4;n++) acc[m][n] = zv;
  }
  g8_core(A, Bt, HIDC, m0, n0, acc, LDS, tid);

  // block-constant output decomposition of the 256-col span
  const int l = n0 / HIDC;
  const int oc0 = n0 - l*HIDC;
  const int lo = lane & 15, hi = lane >> 4;

  #pragma unroll
  for(int pass=0; pass<2; ++pass){
    __syncthreads();            // all mainloop (or prev-pass) LDS reads done
    if(wr == pass){
      #pragma unroll
      for(int m=0;m<8;m++){
        #pragma unroll
        for(int n=0;n<4;n++){
          int col = (wc<<6) + (n<<4) + lo;      // 0..255
          float badd = bias[n0 + col];
          #pragma unroll
          for(int r=0;r<4;r++){
            int lr = (m<<4) + (hi<<2) + r;      // 0..127
            *(float*)(LDS + (size_t)lr*1024 + ((col<<2) ^ ((lr&7)<<4))) = acc[m][n][r] + badd;
          }
        }
      }
    }
    __syncthreads();
    // 128 rows x 1024B ; wave wid stores rows wid, wid+8, ...
    #pragma unroll
    for(int i=0;i<16;i++){
      int lr = (i<<3) + wid;
      int rr = m0 + (pass<<7) + lr;             // global token row
      int b = rr >> 9, s = rr & 511;
      f32x4 v = *(const f32x4*)(LDS + (size_t)lr*1024 + ((lane<<4) ^ ((lr&7)<<4)));
      if(use_mask){ float w = invm[rr]; v = v * w; }
      *(f32x4*)(o + (size_t)((l*4+b)*513 + (s+1))*HIDC + oc0 + (lane<<2)) = v;
    }
  }
}

// ---------- split-K GEMM (m97-style): atomics into GT ----------
__global__ __launch_bounds__(256,2)
void gemm_splitk(const u16* __restrict__ A, const u16* __restrict__ Bt,
                 int M, int N, int K, float* __restrict__ outF, int kchunk){
  __shared__ u16 As[128*64];
  __shared__ u16 Bs[128*64];
  const int t = threadIdx.x;
  const int lane = t & 63;
  const int w = t >> 6;
  const int wr = w >> 1, wc = w & 1;
  int nchunks = (K + kchunk - 1)/kchunk;
  int bm = (int)blockIdx.x / nchunks;
  int ch = (int)blockIdx.x - bm*nchunks;
  int k0 = ch*kchunk, k1 = k0 + kchunk; if(k1 > K) k1 = K;
  const int m0 = bm << 7, n0 = 0;

  f32x4 zv = {0.f,0.f,0.f,0.f};
  f32x4 acc[4][4];
  #pragma unroll
  for(int m=0;m<4;m++){
    #pragma unroll
    for(int n=0;n<4;n++) acc[m][n] = zv;
  }
  const int srow = t >> 3;
  const int scol = (t & 7) << 3;
  const u16* Ag = A + (size_t)(m0 + srow)*K + scol;
  const u16* Bg = Bt + (size_t)(n0 + srow)*K + scol;
  u16* Al = &As[t*8];
  u16* Bl = &Bs[t*8];

  for(int kt=k0; kt<k1; kt+=64){
    __syncthreads();
    #pragma unroll
    for(int i=0;i<4;i++){
      async16(Ag + (size_t)(i*32)*K + kt, Al + i*2048);
      async16(Bg + (size_t)(i*32)*K + kt, Bl + i*2048);
    }
    __syncthreads();
    #pragma unroll
    for(int kk=0; kk<64; kk+=32){
      const int ko = kk + ((lane>>4)<<3);
      short8 af[4], bfv[4];
      #pragma unroll
      for(int m=0;m<4;m++) af[m] = *(const short8*)&As[((wr<<6)+(m<<4)+(lane&15))*64 + ko];
      #pragma unroll
      for(int n=0;n<4;n++) bfv[n] = *(const short8*)&Bs[((wc<<6)+(n<<4)+(lane&15))*64 + ko];
      #pragma unroll
      for(int m=0;m<4;m++){
        #pragma unroll
        for(int n=0;n<4;n++) mfma16(acc[m][n], af[m], bfv[n]);
      }
    }
  }
  const int rbase = (lane>>4)<<2;
  const int cbase = lane & 15;
  #pragma unroll
  for(int m=0;m<4;m++){
    int row0 = m0 + (wr<<6) + (m<<4) + rbase;
    #pragma unroll
    for(int n=0;n<4;n++){
      int col = n0 + (wc<<6) + (n<<4) + cbase;
      #pragma unroll
      for(int r=0;r<4;r++) atomicAdd(&outF[(size_t)(row0+r)*N + col], acc[m][n][r]);
    }
  }
}

// ---------- host ----------
extern "C" void kernel_launch(void* const* d_in, const int* in_sizes, int n_in,
                              void* d_out, int out_size, void* d_ws, size_t ws_size,
                              hipStream_t stream){
  const float* word  = (const float*)d_in[0];
  const int*   ids   = (const int*)d_in[1];
  const int*   cids  = (const int*)d_in[2];
  const void*  mask  = d_in[3];
  const int*   co_ei = (const int*)d_in[4];
  const float* co_ew = (const float*)d_in[5];
  const int*   re_ei = (const int*)d_in[6];
  const float* re_ew = (const float*)d_in[7];
  const float* png   = (const float*)d_in[8];
  const float* co_W  = (const float*)d_in[9];
  const float* co_b  = (const float*)d_in[10];
  const float* re_W  = (const float*)d_in[11];
  const float* re_b  = (const float*)d_in[12];
  const float* pn_W  = (const float*)d_in[13];
  const float* pn_b  = (const float*)d_in[14];
  const float* zw    = (const float*)d_in[15];
  const float* zb    = (const float*)d_in[16];
  const float* zwp   = (const float*)d_in[17];
  const float* zbp   = (const float*)d_in[18];
  float* out = (float*)d_out;

  // opt-in to 128 KiB dynamic LDS (idempotent, host-side, capture-safe)
  hipFuncSetAttribute((const void*)gemm8p_bf16<0>, hipFuncAttributeMaxDynamicSharedMemorySize, G8_LDS);
  hipFuncSetAttribute((const void*)gemm8p_bf16<2>, hipFuncAttributeMaxDynamicSharedMemorySize, G8_LDS);
  hipFuncSetAttribute((const void*)gemm8p_zc,      hipFuncAttributeMaxDynamicSharedMemorySize, G8_LDS);

  char* wsb = (char*)d_ws;
  size_t off = 0;
  auto alloc = [&](size_t bytes)->void*{ void* p = wsb + off; off += (bytes + 255) & ~(size_t)255; return p; };
  u16* WORDB = (u16*)alloc((size_t)M_PAD*HIDC*2);
  u16* BUFB  = (u16*)alloc((size_t)M_PAD*HIDC*2);
  u16* BUFX  = (u16*)alloc((size_t)M_PAD*HIDC*2);
  u16* ZWALL = (u16*)alloc((size_t)2*ZNC*HIDC*2);
  u16* WT2   = (u16*)alloc((size_t)2*3*HIDC*HIDC*2);
  u16* PNWB  = (u16*)alloc((size_t)HIDC*HIDC*2);
  u16* PNB   = (u16*)alloc((size_t)128*M_PAD*2);
  u16* TOKALL= (u16*)alloc((size_t)3*TOKM*HIDC*2);
  float2* TOKF = (float2*)alloc((size_t)TOKM*HIDC*4);
  float* GT   = (float*)alloc((size_t)HIDC*128*4);
  float* DEG2 = (float*)alloc((size_t)2*N_NODESC*4);
  int*   CNT2 = (int*)alloc((size_t)2*N_NODESC*4);
  float* DINVA = (float*)alloc((size_t)2*N_NODESC*4);
  float* DINVB = (float*)alloc((size_t)2*N_NODESC*4);
  int*   RP2  = (int*)alloc((size_t)2*NN1*4);
  int*   CUR2 = (int*)alloc((size_t)2*N_NODESC*4);
  int*   PART2= (int*)alloc((size_t)2*NBLK*4);
  float2* EMETA=(float2*)alloc((size_t)2*NEC*8);
  u32*   NEED = (u32*)alloc((size_t)N_NODESC*4);
  float* INVM = (float*)alloc((size_t)TOKM*4);
  (void)ws_size; (void)in_sizes; (void)n_in; (void)out_size;

  const int GD_TOK = (TOKM*384 + 255)/256;
  const int GD_E   = (NEC + 255)/256;
  const int SPMM_GD  = (N_NODESC + 3)/4;
  const int PN_NCHUNKS = M_PAD/PN_KCHUNK;               // 60
  const int G_PN  = (HIDC/128)*PN_NCHUNKS;              // 360
  const int G8_GCN = (M_PAD/256)*(HIDC/256);            // 360
  const int G8_CBT = (HIDC/256)*(M_PAD/256);            // 360
  const int G8_ZC  = (TOKM/256)*(ZNC/256);              // 288

  // ---- prep ----
  hipMemsetAsync(NEED, 0, (size_t)N_NODESC*4, stream);
  hipMemsetAsync(DEG2, 0, (size_t)2*N_NODESC*4, stream);
  hipMemsetAsync(CNT2, 0, (size_t)2*N_NODESC*4, stream);
  k_invmask<<<1,256,0,stream>>>(mask, INVM);
  k_needed<<<(TOKM+255)/256,256,0,stream>>>(ids, NEED);
  k_conv<<<(HIDC*HIDC/2 + 255)/256,256,0,stream>>>(pn_W, PNWB, HIDC*HIDC/2);
  k_conv<<<(ZNC*HIDC/2 + 255)/256,256,0,stream>>>(zw, ZWALL, ZNC*HIDC/2);
  k_conv<<<(ZNC*HIDC/2 + 255)/256,256,0,stream>>>(zwp, ZWALL + (size_t)ZNC*HIDC, ZNC*HIDC/2);
  k_conv_pad<<<(M_PAD*384 + 255)/256,256,0,stream>>>(word, WORDB, N_NODESC, M_PAD);
  k_transposeW2<<<dim3((3*HIDC*384 + 255)/256, 2),256,0,stream>>>(co_W, re_W, WT2);

  // ---- batched CSR build ----
  k_degcnt2<<<dim3(GD_E,2),256,0,stream>>>(co_ei, re_ei, co_ew, re_ew, DEG2, CNT2);
  k_dinv2<<<dim3((N_NODESC+255)/256,2),256,0,stream>>>(DEG2, DINVA, DINVB);
  k_scan1<<<dim3(NBLK,2),256,0,stream>>>(CNT2, PART2);
  k_scan2<<<2,128,0,stream>>>(PART2, RP2);
  k_scan3<<<dim3(NBLK,2),256,0,stream>>>(CNT2, PART2, RP2, CUR2);
  k_scatter2<<<dim3(GD_E,2),256,0,stream>>>(co_ei, re_ei, co_ew, re_ew, DINVA, CUR2, EMETA);

  // ---- pn path: cbT = pnW·word^T (+row bias), GT = cbT·pn^T (split-K), gather ----
  gemm8p_bf16<2><<<G8_CBT,512,G8_LDS,stream>>>(PNWB, WORDB, HIDC, M_PAD, HIDC, BUFX, pn_b);
  k_pnb<<<(128*(M_PAD/2) + 255)/256,256,0,stream>>>(png, PNB);
  hipMemsetAsync(GT, 0, (size_t)HIDC*128*4, stream);
  gemm_splitk<<<G_PN,256,0,stream>>>(BUFX, PNB, HIDC, 128, M_PAD, GT, PN_KCHUNK);
  k_gather_pn<<<GD_TOK,256,0,stream>>>(GT, cids, TOKALL + (size_t)2*TOKM*HIDC);

  // ---- GCN stacks ----
  auto run_graph = [&](int g, const float* bf, u16* tokb){
    const int* rp = RP2 + (size_t)g*NN1;
    const float2* em = EMETA + (size_t)g*NEC;
    const float* di2 = DINVB + (size_t)g*N_NODESC;
    const u16* X = WORDB;
    for(int i=0;i<3;i++){
      gemm8p_bf16<0><<<G8_GCN,512,G8_LDS,stream>>>(X, WT2 + ((size_t)g*3 + i)*HIDC*HIDC,
                                                   M_PAD, HIDC, HIDC, BUFB, nullptr);
      k_spmm<<<SPMM_GD,256,0,stream>>>(BUFB, rp, em, di2, bf + i*HIDC, BUFX,
                                       (i==2) ? NEED : nullptr);
      k_gather<<<GD_TOK,256,0,stream>>>(BUFX, ids, TOKF, tokb, i);
      X = BUFX;
    }
  };
  run_graph(0, co_b, TOKALL);
  run_graph(1, re_b, TOKALL + (size_t)TOKM*HIDC);

  // ---- zero-convs -> outputs ----
  dim3 zgrid(G8_ZC, 1, 3);
  gemm8p_zc<<<zgrid,512,G8_LDS,stream>>>(TOKALL, ZWALL, zb, zbp, INVM, out);
  k_zerocol<<<(3*LLAY*4*HIDC + 255)/256,256,0,stream>>>(out);
}